// Round 17
// baseline (114.198 us; speedup 1.0000x reference)
//
#include <hip/hip_runtime.h>
#include <hip/hip_bf16.h>

#define B_ 8
#define T_ 4096
#define D_ 128
#define H_ 64
#define SBLK 64
#define NT (T_ / SBLK)

typedef short bf16x8 __attribute__((ext_vector_type(8)));
typedef float f32x4 __attribute__((ext_vector_type(4)));
typedef float f32x16 __attribute__((ext_vector_type(16)));
typedef _Float16 h4 __attribute__((ext_vector_type(4)));

__device__ __forceinline__ unsigned short f2bf(float f) {
  unsigned int u = __float_as_uint(f);
  u += 0x7fffu + ((u >> 16) & 1u);   // RNE
  return (unsigned short)(u >> 16);
}

__device__ __forceinline__ unsigned pk2bf(float lo, float hi) {
  union { __hip_bfloat162 h2; unsigned u; } cv;
  cv.h2 = __float22bfloat162_rn(make_float2(lo, hi));
  return cv.u;
}

__device__ __forceinline__ void async_copy16(const void* g, void* l) {
  __builtin_amdgcn_global_load_lds((const __attribute__((address_space(1))) void*)g,
                                   (__attribute__((address_space(3))) void*)l, 16, 0, 0);
}

// ---- workspace layout (bytes) — r11 layout + optional PH2 tail ----
#define OFF_XP  0u
#define SZ_XP   ((unsigned)(B_*(T_+2)*D_*2))      // padded bf16 X; DEAD after fg -> reused as PH0
#define OFF_XT  (OFF_XP + SZ_XP)
#define SZ_XT   ((unsigned)(B_*D_*T_*2))          // V^T bf16 [B][128][T]
#define OFF_F   (OFF_XT + SZ_XT)
#define SZ_F    ((unsigned)(B_*T_*H_*2))
#define OFF_G   (OFF_F + SZ_F)
#define OFF_WFT (OFF_G + SZ_F)
#define SZ_WFT  ((unsigned)(H_*D_*2))
#define OFF_WGT (OFF_WFT + SZ_WFT)
#define SZ_WGT  ((unsigned)(3*H_*D_*2))
#define OFF_PH1 (OFF_WGT + SZ_WGT)                // fp16 O-partial, split 1
#define SZ_PH   ((unsigned)(B_*T_*D_*2))
#define OFF_PL  (OFF_PH1 + SZ_PH)                 // l-partials [3][B][T] fp32
#define SZ_PL   ((unsigned)(3*B_*T_*4))
#define OFF_PH2 (OFF_PL + SZ_PL)                  // fp16 O-partial, split 2 (optional)
#define WS_NEED ((size_t)(OFF_PH2 + SZ_PH))

// bank-slot swizzle (r4-proven)
#define SLOT(r) (((((r) & 3) << 1) ^ (((r) >> 2) & 1) ^ (((((r) >> 3) ^ ((r) >> 4)) & 1) << 2)))

// ---------------- kernel 1: fused — X -> Xp/XT (y<64) and weight prep (y>=64) ----------------
__global__ __launch_bounds__(256) void prep_xw(const float* __restrict__ X,
                                               const float* __restrict__ Wf,
                                               const float* __restrict__ Wg,
                                               unsigned short* __restrict__ Xp,
                                               unsigned short* __restrict__ XT,
                                               unsigned short* __restrict__ WfT,
                                               unsigned short* __restrict__ WgT) {
  __shared__ unsigned short tile[64][129];   // +1 pad: conflict-free column reads
  const int b = blockIdx.x;
  const int tid = threadIdx.x;

  if (blockIdx.y >= 64) {                    // weight path: 16 blocks x 2048 elements
    const float SC = 0.18033688011112042f;   // (1/sqrt(64)) * log2(e)
    int w = (blockIdx.y - 64) * B_ + b;      // 0..15
#pragma unroll
    for (int i = 0; i < 8; ++i) {
      int idx = w * 2048 + i * 256 + tid;    // 0..32767
      if (idx < H_ * D_) {
        int h = idx >> 7, d = idx & 127;
        WfT[idx] = f2bf(Wf[d * H_ + h] * SC);
      } else {
        int j = idx - H_ * D_;               // 0..24575
        int tap = j >> 13, r = j & 8191;
        int h = r >> 7, d = r & 127;
        WgT[j] = f2bf(Wg[tap * (D_ * H_) + d * H_ + h]);
      }
    }
    return;
  }

  const int t0 = blockIdx.y * 64;
#pragma unroll
  for (int c = 0; c < 8; ++c) {
    int i4 = tid + c * 256;               // 0..2047 float4 chunks of the 64x128 tile
    int row = i4 >> 5, col4 = i4 & 31;
    float4 v = ((const float4*)X)[(size_t)(b * T_ + t0 + row) * 32 + col4];
    ushort4 h;
    h.x = f2bf(v.x); h.y = f2bf(v.y); h.z = f2bf(v.z); h.w = f2bf(v.w);
    ((ushort4*)Xp)[(size_t)(b * (T_ + 2) + 1 + t0 + row) * 32 + col4] = h;
    tile[row][col4 * 4 + 0] = h.x;
    tile[row][col4 * 4 + 1] = h.y;
    tile[row][col4 * 4 + 2] = h.z;
    tile[row][col4 * 4 + 3] = h.w;
  }
  if (blockIdx.y == 0 && tid < 32) {       // zero pad rows (conv boundary)
    ushort4 z = {0, 0, 0, 0};
    ((ushort4*)Xp)[(size_t)(b * (T_ + 2) + 0) * 32 + tid] = z;
    ((ushort4*)Xp)[(size_t)(b * (T_ + 2) + T_ + 1) * 32 + tid] = z;
  }
  __syncthreads();
#pragma unroll
  for (int c = 0; c < 8; ++c) {
    int o4 = tid + c * 256;               // 0..2047 ushort4 chunks of XT tile
    int d = o4 >> 4, t4 = o4 & 15;
    ushort4 h;
    h.x = tile[t4 * 4 + 0][d];
    h.y = tile[t4 * 4 + 1][d];
    h.z = tile[t4 * 4 + 2][d];
    h.w = tile[t4 * 4 + 3][d];
    ((ushort4*)XT)[(size_t)(b * 128 + d) * (T_ / 4) + (t0 >> 2) + t4] = h;
  }
}

// ---------------- kernel 3: F = Xp[t+1]*Wf (pre-scaled), G = sum_taps Xp[t+s]*Wg[s] ----------------
// 32 rows/block, 64-thread blocks (empirically best of all fg variants: r5/r12/r14 all lost).
__global__ __launch_bounds__(64) void fg_kernel(const unsigned short* __restrict__ Xp,
                                                const unsigned short* __restrict__ WfT,
                                                const unsigned short* __restrict__ WgT,
                                                unsigned short* __restrict__ F,
                                                unsigned short* __restrict__ G) {
  const int lane = threadIdx.x;
  const int rowbase = blockIdx.x * 32;         // global (b,t) row
  const int b = rowbase >> 12, t0 = rowbase & (T_ - 1);
  const int l15 = lane & 15, lhi = lane >> 4;
  const f32x4 fz = {0.f, 0.f, 0.f, 0.f};
  f32x4 accF[2][4], accG[2][4];
#pragma unroll
  for (int mt = 0; mt < 2; ++mt)
#pragma unroll
    for (int nt = 0; nt < 4; ++nt) { accF[mt][nt] = fz; accG[mt][nt] = fz; }

#pragma unroll
  for (int kk = 0; kk < 4; ++kk) {
    const int k0 = kk * 32 + lhi * 8;
    bf16x8 a[3][2];
#pragma unroll
    for (int sh = 0; sh < 3; ++sh)
#pragma unroll
      for (int mt = 0; mt < 2; ++mt) {
        int r = b * (T_ + 2) + t0 + sh + mt * 16 + l15;
        a[sh][mt] = *(const bf16x8*)&Xp[(size_t)r * 128 + k0];
      }
#pragma unroll
    for (int nt = 0; nt < 4; ++nt) {
      int h = nt * 16 + l15;
      bf16x8 wf  = *(const bf16x8*)&WfT[h * 128 + k0];
      bf16x8 wg0 = *(const bf16x8*)&WgT[(0 * 64 + h) * 128 + k0];
      bf16x8 wg1 = *(const bf16x8*)&WgT[(1 * 64 + h) * 128 + k0];
      bf16x8 wg2 = *(const bf16x8*)&WgT[(2 * 64 + h) * 128 + k0];
#pragma unroll
      for (int mt = 0; mt < 2; ++mt) {
        accF[mt][nt] = __builtin_amdgcn_mfma_f32_16x16x32_bf16(a[1][mt], wf,  accF[mt][nt], 0, 0, 0);
        accG[mt][nt] = __builtin_amdgcn_mfma_f32_16x16x32_bf16(a[0][mt], wg0, accG[mt][nt], 0, 0, 0);
        accG[mt][nt] = __builtin_amdgcn_mfma_f32_16x16x32_bf16(a[1][mt], wg1, accG[mt][nt], 0, 0, 0);
        accG[mt][nt] = __builtin_amdgcn_mfma_f32_16x16x32_bf16(a[2][mt], wg2, accG[mt][nt], 0, 0, 0);
      }
    }
  }
#pragma unroll
  for (int mt = 0; mt < 2; ++mt)
#pragma unroll
    for (int nt = 0; nt < 4; ++nt)
#pragma unroll
      for (int r = 0; r < 4; ++r) {
        int t = t0 + mt * 16 + lhi * 4 + r;
        int h = nt * 16 + l15;
        size_t o = (size_t)(b * T_ + t) * 64 + h;
        F[o] = f2bf(accF[mt][nt][r]);
        G[o] = f2bf(accG[mt][nt][r]);
      }
}

// ---------------- kernel 4: flash attention — 4-waves/SIMD probe (launch_bounds 256,4) ----------------
// Register-granule model: 512 slots/SIMD; 4 waves need combined <=128 (o_acc 64 AGPR + arch 64).
// Current unconstrained arch = 76; asking the allocator for -12 via the bound. Pre-declared
// failure signature: FETCH/WRITE up (scratch spill) -> revert to (256,3).
__global__ __launch_bounds__(256, 4) void attn_kernel(const unsigned short* __restrict__ F,
                                                      const unsigned short* __restrict__ G,
                                                      const unsigned short* __restrict__ XT,
                                                      float* __restrict__ out,
                                                      _Float16* __restrict__ PH0,
                                                      _Float16* __restrict__ PH1,
                                                      _Float16* __restrict__ PH2,
                                                      float* __restrict__ PL) {
  __shared__ unsigned short klds[2][64 * 64];    // 2 x 8KB,  [s][h] slot-swizzled
  __shared__ unsigned short vlds[2][128 * 64];   // 2 x 16KB, [d][s] slot-swizzled (V^T)
  const int b = blockIdx.x;
  const int q0 = blockIdx.y * 128;
  const int z = blockIdx.z;                      // s-split index (0,1,2)
  const int t_begin = (z == 0) ? 0 : 22 + (z - 1) * 21;   // tiles 22/21/21
  const int t_count = (z == 0) ? 22 : 21;
  const int tid = threadIdx.x;
  const int wave = tid >> 6, lane = tid & 63;
  const int l31 = lane & 31, hi = lane >> 5;
  const int qw = q0 + wave * 32;
  const int E = SLOT(l31) << 4;                  // per-lane read-swizzle constant

  bf16x8 qf[4];
#pragma unroll
  for (int ks = 0; ks < 4; ++ks)
    qf[ks] = *(const bf16x8*)&F[(size_t)(b * T_ + qw + l31) * 64 + ks * 16 + hi * 8];

  f32x16 o_acc[4];
#pragma unroll
  for (int nt = 0; nt < 4; ++nt)
#pragma unroll
    for (int r = 0; r < 16; ++r) o_acc[nt][r] = 0.f;
  float lsum = 0.f;

  const int lo3 = lane >> 3, lc = lane & 7;

  auto stageK = [&](int buf, int gt) {
    const int s0n = gt * SBLK;
#pragma unroll
    for (int i = 0; i < 2; ++i) {
      int kchunk = wave * 2 + i;                 // rows s = kchunk*8 + lo3
      int s = kchunk * 8 + lo3;
      int cp = lc ^ ((lo3 & 3) << 1) ^ ((lo3 >> 2) & 1) ^ (((kchunk ^ (kchunk >> 1)) & 1) << 2);
      async_copy16(&G[(size_t)(b * T_ + s0n + s) * 64 + cp * 8],
                   (char*)&klds[buf][0] + kchunk * 1024);
    }
  };
  auto stageV = [&](int buf, int gt) {
    const int s0n = gt * SBLK;
#pragma unroll
    for (int i = 0; i < 4; ++i) {
      int vchunk = wave * 4 + i;                 // rows d = vchunk*8 + lo3
      int d = vchunk * 8 + lo3;
      int cp = lc ^ ((lo3 & 3) << 1) ^ ((lo3 >> 2) & 1) ^ (((vchunk ^ (vchunk >> 1)) & 1) << 2);
      async_copy16(&XT[(size_t)(b * 128 + d) * T_ + s0n + cp * 8],
                   (char*)&vlds[buf][0] + vchunk * 1024);
    }
  };

  union PW { unsigned u[4]; bf16x8 v; };
  auto makePA = [&](const f32x16& S, bf16x8& paA, bf16x8& paB) {
    float p[16];
#pragma unroll
    for (int r = 0; r < 16; ++r) p[r] = __builtin_amdgcn_exp2f(S[r]);
    lsum += (((p[0] + p[1]) + (p[2] + p[3])) + ((p[4] + p[5]) + (p[6] + p[7])))
          + (((p[8] + p[9]) + (p[10] + p[11])) + ((p[12] + p[13]) + (p[14] + p[15])));
    unsigned w[4][2];
#pragma unroll
    for (int g = 0; g < 4; ++g)
#pragma unroll
      for (int u = 0; u < 2; ++u)
        w[g][u] = pk2bf(p[4 * g + 2 * u], p[4 * g + 2 * u + 1]);
    PW pwA, pwB;
#pragma unroll
    for (int u = 0; u < 2; ++u) {
      unsigned A = w[0][u], Bv = w[1][u];
      asm("v_permlane32_swap_b32 %0, %1" : "+v"(A), "+v"(Bv));
      pwA.u[u] = A; pwA.u[2 + u] = Bv;
    }
#pragma unroll
    for (int u = 0; u < 2; ++u) {
      unsigned A = w[2][u], Bv = w[3][u];
      asm("v_permlane32_swap_b32 %0, %1" : "+v"(A), "+v"(Bv));
      pwB.u[u] = A; pwB.u[2 + u] = Bv;
    }
    paA = pwA.v; paB = pwB.v;
  };

  stageK(0, t_begin);
  stageV(0, t_begin);
  __syncthreads();

  for (int tt = 0; tt < t_count; ++tt) {
    const int cur = tt & 1;
    if (tt + 1 < t_count) {
      stageK(cur ^ 1, t_begin + tt + 1);
      stageV(cur ^ 1, t_begin + tt + 1);
    }

    char* kbase = (char*)klds[cur];
    char* vbase = (char*)vlds[cur];
    bf16x8 pa0, pa1, pa2, pa3;

    __builtin_amdgcn_s_setprio(1);
    {
      f32x16 S0;
#pragma unroll
      for (int r = 0; r < 16; ++r) S0[r] = 0.f;
#pragma unroll
      for (int ks = 0; ks < 4; ++ks) {
        bf16x8 k0 = *(const bf16x8*)(kbase + ((0 * 32 + l31) * 128 + ((ks * 32 + hi * 16) ^ E)));
        S0 = __builtin_amdgcn_mfma_f32_32x32x16_bf16(k0, qf[ks], S0, 0, 0, 0);
      }
      makePA(S0, pa0, pa1);
    }
    {
      f32x16 S1;
#pragma unroll
      for (int r = 0; r < 16; ++r) S1[r] = 0.f;
#pragma unroll
      for (int ks = 0; ks < 4; ++ks) {
        bf16x8 k1 = *(const bf16x8*)(kbase + ((1 * 32 + l31) * 128 + ((ks * 32 + hi * 16) ^ E)));
        S1 = __builtin_amdgcn_mfma_f32_32x32x16_bf16(k1, qf[ks], S1, 0, 0, 0);
      }
      makePA(S1, pa2, pa3);
    }

#pragma unroll
    for (int nt = 0; nt < 4; ++nt) {
      bf16x8 vf0 = *(const bf16x8*)(vbase + ((nt * 32 + l31) * 128 + ((0 * 32 + hi * 16) ^ E)));
      bf16x8 vf1 = *(const bf16x8*)(vbase + ((nt * 32 + l31) * 128 + ((1 * 32 + hi * 16) ^ E)));
      bf16x8 vf2 = *(const bf16x8*)(vbase + ((nt * 32 + l31) * 128 + ((2 * 32 + hi * 16) ^ E)));
      bf16x8 vf3 = *(const bf16x8*)(vbase + ((nt * 32 + l31) * 128 + ((3 * 32 + hi * 16) ^ E)));
      o_acc[nt] = __builtin_amdgcn_mfma_f32_32x32x16_bf16(pa0, vf0, o_acc[nt], 0, 0, 0);
      o_acc[nt] = __builtin_amdgcn_mfma_f32_32x32x16_bf16(pa1, vf1, o_acc[nt], 0, 0, 0);
      o_acc[nt] = __builtin_amdgcn_mfma_f32_32x32x16_bf16(pa2, vf2, o_acc[nt], 0, 0, 0);
      o_acc[nt] = __builtin_amdgcn_mfma_f32_32x32x16_bf16(pa3, vf3, o_acc[nt], 0, 0, 0);
    }
    __builtin_amdgcn_s_setprio(0);
    __syncthreads();                 // single barrier: publishes reads, drains prefetch
  }

  // epilogue: RAW partials. Row q = (r&3)+8*(r>>2)+4*hi, col d = nt*32+l31.
  if (z == 2) {
    if (PH2) {                       // merge-diet path: fp16 partial, no out round-trip
#pragma unroll
      for (int r = 0; r < 16; ++r) {
        int trow = qw + (r & 3) + 8 * (r >> 2) + 4 * hi;
#pragma unroll
        for (int nt = 0; nt < 4; ++nt)
          PH2[(size_t)(b * T_ + trow) * 128 + nt * 32 + l31] = (_Float16)o_acc[nt][r];
      }
    } else {                         // fallback: r15-identical
#pragma unroll
      for (int r = 0; r < 16; ++r) {
        int trow = qw + (r & 3) + 8 * (r >> 2) + 4 * hi;
#pragma unroll
        for (int nt = 0; nt < 4; ++nt)
          out[(size_t)(b * T_ + trow) * 128 + nt * 32 + l31] = o_acc[nt][r];
      }
    }
  } else {
    _Float16* ph = z ? PH1 : PH0;
#pragma unroll
    for (int r = 0; r < 16; ++r) {
      int trow = qw + (r & 3) + 8 * (r >> 2) + 4 * hi;
#pragma unroll
      for (int nt = 0; nt < 4; ++nt)
        ph[(size_t)(b * T_ + trow) * 128 + nt * 32 + l31] = (_Float16)o_acc[nt][r];
    }
  }
  lsum += __shfl_xor(lsum, 32, 64);
  if (hi == 0)
    PL[z * (B_ * T_) + b * T_ + qw + l31] = lsum;
}

// ---------------- kernel 5: out = (sum partials) / (l0 + l1 + l2) ----------------
__global__ __launch_bounds__(256) void merge_kernel(const _Float16* __restrict__ PH0,
                                                    const _Float16* __restrict__ PH1,
                                                    const _Float16* __restrict__ PH2,
                                                    const float* __restrict__ PL,
                                                    float* __restrict__ out,
                                                    int use2) {
  int idx = blockIdx.x * 256 + threadIdx.x;      // float4 index, 0..B*T*D/4-1
  int row = idx >> 5;                            // b*T + t
  h4 p0 = *(const h4*)&PH0[(size_t)idx * 4];
  h4 p1 = *(const h4*)&PH1[(size_t)idx * 4];
  float ax = (float)p0.x + (float)p1.x;
  float ay = (float)p0.y + (float)p1.y;
  float az = (float)p0.z + (float)p1.z;
  float aw = (float)p0.w + (float)p1.w;
  if (use2) {
    h4 p2 = *(const h4*)&PH2[(size_t)idx * 4];
    ax += (float)p2.x; ay += (float)p2.y; az += (float)p2.z; aw += (float)p2.w;
  } else {
    float4 o = ((const float4*)out)[idx];
    ax += o.x; ay += o.y; az += o.z; aw += o.w;
  }
  float inv = 1.0f / (PL[row] + PL[B_ * T_ + row] + PL[2 * B_ * T_ + row]);
  float4 r;
  r.x = ax * inv;
  r.y = ay * inv;
  r.z = az * inv;
  r.w = aw * inv;
  ((float4*)out)[idx] = r;
}

extern "C" void kernel_launch(void* const* d_in, const int* in_sizes, int n_in,
                              void* d_out, int out_size, void* d_ws, size_t ws_size,
                              hipStream_t stream) {
  (void)in_sizes; (void)n_in; (void)out_size;
  const float* X  = (const float*)d_in[0];
  const float* Wf = (const float*)d_in[1];
  const float* Wg = (const float*)d_in[2];
  float* out = (float*)d_out;
  char* ws = (char*)d_ws;
  unsigned short* Xp  = (unsigned short*)(ws + OFF_XP);
  unsigned short* XT  = (unsigned short*)(ws + OFF_XT);
  unsigned short* Fb  = (unsigned short*)(ws + OFF_F);
  unsigned short* Gb  = (unsigned short*)(ws + OFF_G);
  unsigned short* WfT = (unsigned short*)(ws + OFF_WFT);
  unsigned short* WgT = (unsigned short*)(ws + OFF_WGT);
  _Float16* PH0 = (_Float16*)(ws + OFF_XP);      // overlays Xp (dead after fg_kernel)
  _Float16* PH1 = (_Float16*)(ws + OFF_PH1);
  float* PL  = (float*)(ws + OFF_PL);

  const int use2 = (ws_size >= WS_NEED) ? 1 : 0; // deterministic per-run
  _Float16* PH2 = use2 ? (_Float16*)(ws + OFF_PH2) : nullptr;

  prep_xw<<<dim3(B_, 66), 256, 0, stream>>>(X, Wf, Wg, Xp, XT, WfT, WgT);
  fg_kernel<<<(B_ * T_) / 32, 64, 0, stream>>>(Xp, WfT, WgT, Fb, Gb);
  attn_kernel<<<dim3(B_, T_ / 128, 3), 256, 0, stream>>>(Fb, Gb, XT, out, PH0, PH1, PH2, PL);
  merge_kernel<<<(B_ * T_ * D_ / 4) / 256, 256, 0, stream>>>(PH0, PH1, PH2, PL, out, use2);
}

// Round 18
// 93.821 us; speedup vs baseline: 1.2172x; 1.2172x over previous
//
#include <hip/hip_runtime.h>
#include <hip/hip_bf16.h>

#define B_ 8
#define T_ 4096
#define D_ 128
#define H_ 64
#define SBLK 64
#define NT (T_ / SBLK)

typedef short bf16x8 __attribute__((ext_vector_type(8)));
typedef float f32x4 __attribute__((ext_vector_type(4)));
typedef float f32x16 __attribute__((ext_vector_type(16)));
typedef _Float16 h4 __attribute__((ext_vector_type(4)));

__device__ __forceinline__ unsigned short f2bf(float f) {
  unsigned int u = __float_as_uint(f);
  u += 0x7fffu + ((u >> 16) & 1u);   // RNE
  return (unsigned short)(u >> 16);
}

__device__ __forceinline__ unsigned pk2bf(float lo, float hi) {
  union { __hip_bfloat162 h2; unsigned u; } cv;
  cv.h2 = __float22bfloat162_rn(make_float2(lo, hi));
  return cv.u;
}

__device__ __forceinline__ void async_copy16(const void* g, void* l) {
  __builtin_amdgcn_global_load_lds((const __attribute__((address_space(1))) void*)g,
                                   (__attribute__((address_space(3))) void*)l, 16, 0, 0);
}

// ---- workspace layout (bytes) — r11 layout + optional PH2 tail ----
#define OFF_XP  0u
#define SZ_XP   ((unsigned)(B_*(T_+2)*D_*2))      // padded bf16 X; DEAD after fg -> reused as PH0
#define OFF_XT  (OFF_XP + SZ_XP)
#define SZ_XT   ((unsigned)(B_*D_*T_*2))          // V^T bf16 [B][128][T]
#define OFF_F   (OFF_XT + SZ_XT)
#define SZ_F    ((unsigned)(B_*T_*H_*2))
#define OFF_G   (OFF_F + SZ_F)
#define OFF_WFT (OFF_G + SZ_F)
#define SZ_WFT  ((unsigned)(H_*D_*2))
#define OFF_WGT (OFF_WFT + SZ_WFT)
#define SZ_WGT  ((unsigned)(3*H_*D_*2))
#define OFF_PH1 (OFF_WGT + SZ_WGT)                // fp16 O-partial, split 1
#define SZ_PH   ((unsigned)(B_*T_*D_*2))
#define OFF_PL  (OFF_PH1 + SZ_PH)                 // l-partials [3][B][T] fp32
#define SZ_PL   ((unsigned)(3*B_*T_*4))
#define OFF_PH2 (OFF_PL + SZ_PL)                  // fp16 O-partial, split 2 (optional)
#define WS_NEED ((size_t)(OFF_PH2 + SZ_PH))

// bank-slot swizzle (r4-proven)
#define SLOT(r) (((((r) & 3) << 1) ^ (((r) >> 2) & 1) ^ (((((r) >> 3) ^ ((r) >> 4)) & 1) << 2)))

// ---------------- kernel 1: fused — X -> Xp/XT (y<64) and weight prep (y>=64) ----------------
__global__ __launch_bounds__(256) void prep_xw(const float* __restrict__ X,
                                               const float* __restrict__ Wf,
                                               const float* __restrict__ Wg,
                                               unsigned short* __restrict__ Xp,
                                               unsigned short* __restrict__ XT,
                                               unsigned short* __restrict__ WfT,
                                               unsigned short* __restrict__ WgT) {
  __shared__ unsigned short tile[64][129];   // +1 pad: conflict-free column reads
  const int b = blockIdx.x;
  const int tid = threadIdx.x;

  if (blockIdx.y >= 64) {                    // weight path: 16 blocks x 2048 elements
    const float SC = 0.18033688011112042f;   // (1/sqrt(64)) * log2(e)
    int w = (blockIdx.y - 64) * B_ + b;      // 0..15
#pragma unroll
    for (int i = 0; i < 8; ++i) {
      int idx = w * 2048 + i * 256 + tid;    // 0..32767
      if (idx < H_ * D_) {
        int h = idx >> 7, d = idx & 127;
        WfT[idx] = f2bf(Wf[d * H_ + h] * SC);
      } else {
        int j = idx - H_ * D_;               // 0..24575
        int tap = j >> 13, r = j & 8191;
        int h = r >> 7, d = r & 127;
        WgT[j] = f2bf(Wg[tap * (D_ * H_) + d * H_ + h]);
      }
    }
    return;
  }

  const int t0 = blockIdx.y * 64;
#pragma unroll
  for (int c = 0; c < 8; ++c) {
    int i4 = tid + c * 256;               // 0..2047 float4 chunks of the 64x128 tile
    int row = i4 >> 5, col4 = i4 & 31;
    float4 v = ((const float4*)X)[(size_t)(b * T_ + t0 + row) * 32 + col4];
    ushort4 h;
    h.x = f2bf(v.x); h.y = f2bf(v.y); h.z = f2bf(v.z); h.w = f2bf(v.w);
    ((ushort4*)Xp)[(size_t)(b * (T_ + 2) + 1 + t0 + row) * 32 + col4] = h;
    tile[row][col4 * 4 + 0] = h.x;
    tile[row][col4 * 4 + 1] = h.y;
    tile[row][col4 * 4 + 2] = h.z;
    tile[row][col4 * 4 + 3] = h.w;
  }
  if (blockIdx.y == 0 && tid < 32) {       // zero pad rows (conv boundary)
    ushort4 z = {0, 0, 0, 0};
    ((ushort4*)Xp)[(size_t)(b * (T_ + 2) + 0) * 32 + tid] = z;
    ((ushort4*)Xp)[(size_t)(b * (T_ + 2) + T_ + 1) * 32 + tid] = z;
  }
  __syncthreads();
#pragma unroll
  for (int c = 0; c < 8; ++c) {
    int o4 = tid + c * 256;               // 0..2047 ushort4 chunks of XT tile
    int d = o4 >> 4, t4 = o4 & 15;
    ushort4 h;
    h.x = tile[t4 * 4 + 0][d];
    h.y = tile[t4 * 4 + 1][d];
    h.z = tile[t4 * 4 + 2][d];
    h.w = tile[t4 * 4 + 3][d];
    ((ushort4*)XT)[(size_t)(b * 128 + d) * (T_ / 4) + (t0 >> 2) + t4] = h;
  }
}

// ---------------- kernel 3: F = Xp[t+1]*Wf (pre-scaled), G = sum_taps Xp[t+s]*Wg[s] ----------------
// 32 rows/block, 64-thread blocks (empirically best of all fg variants: r5/r12/r14 all lost).
__global__ __launch_bounds__(64) void fg_kernel(const unsigned short* __restrict__ Xp,
                                                const unsigned short* __restrict__ WfT,
                                                const unsigned short* __restrict__ WgT,
                                                unsigned short* __restrict__ F,
                                                unsigned short* __restrict__ G) {
  const int lane = threadIdx.x;
  const int rowbase = blockIdx.x * 32;         // global (b,t) row
  const int b = rowbase >> 12, t0 = rowbase & (T_ - 1);
  const int l15 = lane & 15, lhi = lane >> 4;
  const f32x4 fz = {0.f, 0.f, 0.f, 0.f};
  f32x4 accF[2][4], accG[2][4];
#pragma unroll
  for (int mt = 0; mt < 2; ++mt)
#pragma unroll
    for (int nt = 0; nt < 4; ++nt) { accF[mt][nt] = fz; accG[mt][nt] = fz; }

#pragma unroll
  for (int kk = 0; kk < 4; ++kk) {
    const int k0 = kk * 32 + lhi * 8;
    bf16x8 a[3][2];
#pragma unroll
    for (int sh = 0; sh < 3; ++sh)
#pragma unroll
      for (int mt = 0; mt < 2; ++mt) {
        int r = b * (T_ + 2) + t0 + sh + mt * 16 + l15;
        a[sh][mt] = *(const bf16x8*)&Xp[(size_t)r * 128 + k0];
      }
#pragma unroll
    for (int nt = 0; nt < 4; ++nt) {
      int h = nt * 16 + l15;
      bf16x8 wf  = *(const bf16x8*)&WfT[h * 128 + k0];
      bf16x8 wg0 = *(const bf16x8*)&WgT[(0 * 64 + h) * 128 + k0];
      bf16x8 wg1 = *(const bf16x8*)&WgT[(1 * 64 + h) * 128 + k0];
      bf16x8 wg2 = *(const bf16x8*)&WgT[(2 * 64 + h) * 128 + k0];
#pragma unroll
      for (int mt = 0; mt < 2; ++mt) {
        accF[mt][nt] = __builtin_amdgcn_mfma_f32_16x16x32_bf16(a[1][mt], wf,  accF[mt][nt], 0, 0, 0);
        accG[mt][nt] = __builtin_amdgcn_mfma_f32_16x16x32_bf16(a[0][mt], wg0, accG[mt][nt], 0, 0, 0);
        accG[mt][nt] = __builtin_amdgcn_mfma_f32_16x16x32_bf16(a[1][mt], wg1, accG[mt][nt], 0, 0, 0);
        accG[mt][nt] = __builtin_amdgcn_mfma_f32_16x16x32_bf16(a[2][mt], wg2, accG[mt][nt], 0, 0, 0);
      }
    }
  }
#pragma unroll
  for (int mt = 0; mt < 2; ++mt)
#pragma unroll
    for (int nt = 0; nt < 4; ++nt)
#pragma unroll
      for (int r = 0; r < 4; ++r) {
        int t = t0 + mt * 16 + lhi * 4 + r;
        int h = nt * 16 + l15;
        size_t o = (size_t)(b * T_ + t) * 64 + h;
        F[o] = f2bf(accF[mt][nt][r]);
        G[o] = f2bf(accG[mt][nt][r]);
      }
}

// ---------------- kernel 4: flash attention (r16 best-known: (256,3), 3 waves/SIMD) ----------------
// Unified VGPR+AGPR file is the binding constraint: 76 arch + 64 AGPR ~ 140 <= 3x160 granule.
// (256,4) probe (r17): infeasible bound perturbed regalloc to 108 VGPR, 2 waves, -38% — closed.
__global__ __launch_bounds__(256, 3) void attn_kernel(const unsigned short* __restrict__ F,
                                                      const unsigned short* __restrict__ G,
                                                      const unsigned short* __restrict__ XT,
                                                      float* __restrict__ out,
                                                      _Float16* __restrict__ PH0,
                                                      _Float16* __restrict__ PH1,
                                                      _Float16* __restrict__ PH2,
                                                      float* __restrict__ PL) {
  __shared__ unsigned short klds[2][64 * 64];    // 2 x 8KB,  [s][h] slot-swizzled
  __shared__ unsigned short vlds[2][128 * 64];   // 2 x 16KB, [d][s] slot-swizzled (V^T)
  const int b = blockIdx.x;
  const int q0 = blockIdx.y * 128;
  const int z = blockIdx.z;                      // s-split index (0,1,2)
  const int t_begin = (z == 0) ? 0 : 22 + (z - 1) * 21;   // tiles 22/21/21
  const int t_count = (z == 0) ? 22 : 21;
  const int tid = threadIdx.x;
  const int wave = tid >> 6, lane = tid & 63;
  const int l31 = lane & 31, hi = lane >> 5;
  const int qw = q0 + wave * 32;
  const int E = SLOT(l31) << 4;                  // per-lane read-swizzle constant

  bf16x8 qf[4];
#pragma unroll
  for (int ks = 0; ks < 4; ++ks)
    qf[ks] = *(const bf16x8*)&F[(size_t)(b * T_ + qw + l31) * 64 + ks * 16 + hi * 8];

  f32x16 o_acc[4];
#pragma unroll
  for (int nt = 0; nt < 4; ++nt)
#pragma unroll
    for (int r = 0; r < 16; ++r) o_acc[nt][r] = 0.f;
  float lsum = 0.f;

  const int lo3 = lane >> 3, lc = lane & 7;

  auto stageK = [&](int buf, int gt) {
    const int s0n = gt * SBLK;
#pragma unroll
    for (int i = 0; i < 2; ++i) {
      int kchunk = wave * 2 + i;                 // rows s = kchunk*8 + lo3
      int s = kchunk * 8 + lo3;
      int cp = lc ^ ((lo3 & 3) << 1) ^ ((lo3 >> 2) & 1) ^ (((kchunk ^ (kchunk >> 1)) & 1) << 2);
      async_copy16(&G[(size_t)(b * T_ + s0n + s) * 64 + cp * 8],
                   (char*)&klds[buf][0] + kchunk * 1024);
    }
  };
  auto stageV = [&](int buf, int gt) {
    const int s0n = gt * SBLK;
#pragma unroll
    for (int i = 0; i < 4; ++i) {
      int vchunk = wave * 4 + i;                 // rows d = vchunk*8 + lo3
      int d = vchunk * 8 + lo3;
      int cp = lc ^ ((lo3 & 3) << 1) ^ ((lo3 >> 2) & 1) ^ (((vchunk ^ (vchunk >> 1)) & 1) << 2);
      async_copy16(&XT[(size_t)(b * 128 + d) * T_ + s0n + cp * 8],
                   (char*)&vlds[buf][0] + vchunk * 1024);
    }
  };

  union PW { unsigned u[4]; bf16x8 v; };
  auto makePA = [&](const f32x16& S, bf16x8& paA, bf16x8& paB) {
    float p[16];
#pragma unroll
    for (int r = 0; r < 16; ++r) p[r] = __builtin_amdgcn_exp2f(S[r]);
    lsum += (((p[0] + p[1]) + (p[2] + p[3])) + ((p[4] + p[5]) + (p[6] + p[7])))
          + (((p[8] + p[9]) + (p[10] + p[11])) + ((p[12] + p[13]) + (p[14] + p[15])));
    unsigned w[4][2];
#pragma unroll
    for (int g = 0; g < 4; ++g)
#pragma unroll
      for (int u = 0; u < 2; ++u)
        w[g][u] = pk2bf(p[4 * g + 2 * u], p[4 * g + 2 * u + 1]);
    PW pwA, pwB;
#pragma unroll
    for (int u = 0; u < 2; ++u) {
      unsigned A = w[0][u], Bv = w[1][u];
      asm("v_permlane32_swap_b32 %0, %1" : "+v"(A), "+v"(Bv));
      pwA.u[u] = A; pwA.u[2 + u] = Bv;
    }
#pragma unroll
    for (int u = 0; u < 2; ++u) {
      unsigned A = w[2][u], Bv = w[3][u];
      asm("v_permlane32_swap_b32 %0, %1" : "+v"(A), "+v"(Bv));
      pwB.u[u] = A; pwB.u[2 + u] = Bv;
    }
    paA = pwA.v; paB = pwB.v;
  };

  stageK(0, t_begin);
  stageV(0, t_begin);
  __syncthreads();

  for (int tt = 0; tt < t_count; ++tt) {
    const int cur = tt & 1;
    if (tt + 1 < t_count) {
      stageK(cur ^ 1, t_begin + tt + 1);
      stageV(cur ^ 1, t_begin + tt + 1);
    }

    char* kbase = (char*)klds[cur];
    char* vbase = (char*)vlds[cur];
    bf16x8 pa0, pa1, pa2, pa3;

    __builtin_amdgcn_s_setprio(1);
    {
      f32x16 S0;
#pragma unroll
      for (int r = 0; r < 16; ++r) S0[r] = 0.f;
#pragma unroll
      for (int ks = 0; ks < 4; ++ks) {
        bf16x8 k0 = *(const bf16x8*)(kbase + ((0 * 32 + l31) * 128 + ((ks * 32 + hi * 16) ^ E)));
        S0 = __builtin_amdgcn_mfma_f32_32x32x16_bf16(k0, qf[ks], S0, 0, 0, 0);
      }
      makePA(S0, pa0, pa1);
    }
    {
      f32x16 S1;
#pragma unroll
      for (int r = 0; r < 16; ++r) S1[r] = 0.f;
#pragma unroll
      for (int ks = 0; ks < 4; ++ks) {
        bf16x8 k1 = *(const bf16x8*)(kbase + ((1 * 32 + l31) * 128 + ((ks * 32 + hi * 16) ^ E)));
        S1 = __builtin_amdgcn_mfma_f32_32x32x16_bf16(k1, qf[ks], S1, 0, 0, 0);
      }
      makePA(S1, pa2, pa3);
    }

#pragma unroll
    for (int nt = 0; nt < 4; ++nt) {
      bf16x8 vf0 = *(const bf16x8*)(vbase + ((nt * 32 + l31) * 128 + ((0 * 32 + hi * 16) ^ E)));
      bf16x8 vf1 = *(const bf16x8*)(vbase + ((nt * 32 + l31) * 128 + ((1 * 32 + hi * 16) ^ E)));
      bf16x8 vf2 = *(const bf16x8*)(vbase + ((nt * 32 + l31) * 128 + ((2 * 32 + hi * 16) ^ E)));
      bf16x8 vf3 = *(const bf16x8*)(vbase + ((nt * 32 + l31) * 128 + ((3 * 32 + hi * 16) ^ E)));
      o_acc[nt] = __builtin_amdgcn_mfma_f32_32x32x16_bf16(pa0, vf0, o_acc[nt], 0, 0, 0);
      o_acc[nt] = __builtin_amdgcn_mfma_f32_32x32x16_bf16(pa1, vf1, o_acc[nt], 0, 0, 0);
      o_acc[nt] = __builtin_amdgcn_mfma_f32_32x32x16_bf16(pa2, vf2, o_acc[nt], 0, 0, 0);
      o_acc[nt] = __builtin_amdgcn_mfma_f32_32x32x16_bf16(pa3, vf3, o_acc[nt], 0, 0, 0);
    }
    __builtin_amdgcn_s_setprio(0);
    __syncthreads();                 // single barrier: publishes reads, drains prefetch
  }

  // epilogue: RAW partials. Row q = (r&3)+8*(r>>2)+4*hi, col d = nt*32+l31.
  if (z == 2) {
    if (PH2) {                       // merge-diet path: fp16 partial, no out round-trip
#pragma unroll
      for (int r = 0; r < 16; ++r) {
        int trow = qw + (r & 3) + 8 * (r >> 2) + 4 * hi;
#pragma unroll
        for (int nt = 0; nt < 4; ++nt)
          PH2[(size_t)(b * T_ + trow) * 128 + nt * 32 + l31] = (_Float16)o_acc[nt][r];
      }
    } else {                         // fallback: r15-identical
#pragma unroll
      for (int r = 0; r < 16; ++r) {
        int trow = qw + (r & 3) + 8 * (r >> 2) + 4 * hi;
#pragma unroll
        for (int nt = 0; nt < 4; ++nt)
          out[(size_t)(b * T_ + trow) * 128 + nt * 32 + l31] = o_acc[nt][r];
      }
    }
  } else {
    _Float16* ph = z ? PH1 : PH0;
#pragma unroll
    for (int r = 0; r < 16; ++r) {
      int trow = qw + (r & 3) + 8 * (r >> 2) + 4 * hi;
#pragma unroll
      for (int nt = 0; nt < 4; ++nt)
        ph[(size_t)(b * T_ + trow) * 128 + nt * 32 + l31] = (_Float16)o_acc[nt][r];
    }
  }
  lsum += __shfl_xor(lsum, 32, 64);
  if (hi == 0)
    PL[z * (B_ * T_) + b * T_ + qw + l31] = lsum;
}

// ---------------- kernel 5: out = (sum partials) / (l0 + l1 + l2) ----------------
__global__ __launch_bounds__(256) void merge_kernel(const _Float16* __restrict__ PH0,
                                                    const _Float16* __restrict__ PH1,
                                                    const _Float16* __restrict__ PH2,
                                                    const float* __restrict__ PL,
                                                    float* __restrict__ out,
                                                    int use2) {
  int idx = blockIdx.x * 256 + threadIdx.x;      // float4 index, 0..B*T*D/4-1
  int row = idx >> 5;                            // b*T + t
  h4 p0 = *(const h4*)&PH0[(size_t)idx * 4];
  h4 p1 = *(const h4*)&PH1[(size_t)idx * 4];
  float ax = (float)p0.x + (float)p1.x;
  float ay = (float)p0.y + (float)p1.y;
  float az = (float)p0.z + (float)p1.z;
  float aw = (float)p0.w + (float)p1.w;
  if (use2) {
    h4 p2 = *(const h4*)&PH2[(size_t)idx * 4];
    ax += (float)p2.x; ay += (float)p2.y; az += (float)p2.z; aw += (float)p2.w;
  } else {
    float4 o = ((const float4*)out)[idx];
    ax += o.x; ay += o.y; az += o.z; aw += o.w;
  }
  float inv = 1.0f / (PL[row] + PL[B_ * T_ + row] + PL[2 * B_ * T_ + row]);
  float4 r;
  r.x = ax * inv;
  r.y = ay * inv;
  r.z = az * inv;
  r.w = aw * inv;
  ((float4*)out)[idx] = r;
}

extern "C" void kernel_launch(void* const* d_in, const int* in_sizes, int n_in,
                              void* d_out, int out_size, void* d_ws, size_t ws_size,
                              hipStream_t stream) {
  (void)in_sizes; (void)n_in; (void)out_size;
  const float* X  = (const float*)d_in[0];
  const float* Wf = (const float*)d_in[1];
  const float* Wg = (const float*)d_in[2];
  float* out = (float*)d_out;
  char* ws = (char*)d_ws;
  unsigned short* Xp  = (unsigned short*)(ws + OFF_XP);
  unsigned short* XT  = (unsigned short*)(ws + OFF_XT);
  unsigned short* Fb  = (unsigned short*)(ws + OFF_F);
  unsigned short* Gb  = (unsigned short*)(ws + OFF_G);
  unsigned short* WfT = (unsigned short*)(ws + OFF_WFT);
  unsigned short* WgT = (unsigned short*)(ws + OFF_WGT);
  _Float16* PH0 = (_Float16*)(ws + OFF_XP);      // overlays Xp (dead after fg_kernel)
  _Float16* PH1 = (_Float16*)(ws + OFF_PH1);
  float* PL  = (float*)(ws + OFF_PL);

  const int use2 = (ws_size >= WS_NEED) ? 1 : 0; // deterministic per-run
  _Float16* PH2 = use2 ? (_Float16*)(ws + OFF_PH2) : nullptr;

  prep_xw<<<dim3(B_, 66), 256, 0, stream>>>(X, Wf, Wg, Xp, XT, WfT, WgT);
  fg_kernel<<<(B_ * T_) / 32, 64, 0, stream>>>(Xp, WfT, WgT, Fb, Gb);
  attn_kernel<<<dim3(B_, T_ / 128, 3), 256, 0, stream>>>(Fb, Gb, XT, out, PH0, PH1, PH2, PL);
  merge_kernel<<<(B_ * T_ * D_ / 4) / 256, 256, 0, stream>>>(PH0, PH1, PH2, PL, out, use2);
}